// Round 1
// baseline (806.560 us; speedup 1.0000x reference)
//
#include <hip/hip_runtime.h>
#include <cstdio>

#define T_DIM 2048
#define B_DIM 2
#define E_DIM 1024
#define H_DIM 16
#define S_DIM 64

// ---------------- Kernel 0: transpose Er [S][T] -> ErT [T][S] ----------------
__global__ __launch_bounds__(256) void er_transpose(const float* __restrict__ Er,
                                                    float* __restrict__ ErT) {
    int idx = blockIdx.x * 256 + threadIdx.x;   // T*S = 131072 total
    int t = idx >> 6, d = idx & 63;
    ErT[idx] = Er[d * T_DIM + t];               // write coalesced, read strided (tiny kernel)
}

// ---------------- Kernel 1: QKV projection + k' = k/32 + Er^T ----------------
// grid = B*H*(T/64) = 1024 blocks, 256 threads. Each wave: 16 t-rows, lane = d.
__global__ __launch_bounds__(256) void qkv_kernel(
    const float* __restrict__ x, const float* __restrict__ Wq,
    const float* __restrict__ Wk, const float* __restrict__ Wv,
    const float* __restrict__ ErT,
    float* __restrict__ q, float* __restrict__ kp, float* __restrict__ v)
{
    __shared__ __align__(16) float xs[64][64];   // x tile [t][s]; reads are broadcasts
    int bid = blockIdx.x;
    int tblk = bid & 31;
    int h = (bid >> 5) & 15;
    int b = bid >> 9;
    int t0 = tblk * 64;
    int tid = threadIdx.x;

    // stage x tile: 64 t x 64 s, float4-coalesced
    for (int i = tid; i < 1024; i += 256) {
        int t = i >> 4, c = i & 15;
        const float4* src = reinterpret_cast<const float4*>(
            x + (size_t)(t0 + t) * (B_DIM * E_DIM) + (size_t)b * E_DIM + h * S_DIM) + c;
        reinterpret_cast<float4*>(&xs[t][0])[c] = *src;
    }
    __syncthreads();

    int w = tid >> 6;     // wave id 0..3
    int d = tid & 63;     // output feature (lane)
    float accq[16], acck[16], accv[16];
#pragma unroll
    for (int i = 0; i < 16; ++i) { accq[i] = 0.f; acck[i] = 0.f; accv[i] = 0.f; }

    const float* wqp = Wq + (size_t)h * 4096 + (size_t)d * 64;
    const float* wkp = Wk + (size_t)h * 4096 + (size_t)d * 64;
    const float* wvp = Wv + (size_t)h * 4096 + (size_t)d * 64;

    for (int sc = 0; sc < 4; ++sc) {              // s-chunks of 16
        float wqr[16], wkr[16], wvr[16];
#pragma unroll
        for (int j = 0; j < 4; ++j) {
            float4 a = reinterpret_cast<const float4*>(wqp + sc * 16)[j];
            float4 c2 = reinterpret_cast<const float4*>(wkp + sc * 16)[j];
            float4 e = reinterpret_cast<const float4*>(wvp + sc * 16)[j];
            wqr[j*4+0]=a.x; wqr[j*4+1]=a.y; wqr[j*4+2]=a.z; wqr[j*4+3]=a.w;
            wkr[j*4+0]=c2.x; wkr[j*4+1]=c2.y; wkr[j*4+2]=c2.z; wkr[j*4+3]=c2.w;
            wvr[j*4+0]=e.x; wvr[j*4+1]=e.y; wvr[j*4+2]=e.z; wvr[j*4+3]=e.w;
        }
#pragma unroll
        for (int tt = 0; tt < 16; ++tt) {
            int t = w * 16 + tt;
#pragma unroll
            for (int j = 0; j < 4; ++j) {
                float4 x4 = reinterpret_cast<const float4*>(&xs[t][sc * 16])[j]; // broadcast
                accq[tt] += x4.x*wqr[j*4+0] + x4.y*wqr[j*4+1] + x4.z*wqr[j*4+2] + x4.w*wqr[j*4+3];
                acck[tt] += x4.x*wkr[j*4+0] + x4.y*wkr[j*4+1] + x4.z*wkr[j*4+2] + x4.w*wkr[j*4+3];
                accv[tt] += x4.x*wvr[j*4+0] + x4.y*wvr[j*4+1] + x4.z*wvr[j*4+2] + x4.w*wvr[j*4+3];
            }
        }
    }

    size_t base = ((size_t)(b * H_DIM + h) * T_DIM) * S_DIM;
#pragma unroll
    for (int tt = 0; tt < 16; ++tt) {
        int tg = t0 + w * 16 + tt;
        q [base + (size_t)tg * 64 + d] = accq[tt];
        // k' = k/sqrt(E) + Er[d][t]  (folds srel AND the score scaling into k)
        kp[base + (size_t)tg * 64 + d] = acck[tt] * 0.03125f + ErT[(size_t)tg * 64 + d];
        v [base + (size_t)tg * 64 + d] = accv[tt];
    }
}

// ---------------- Kernel 2: causal flash attention (fp32) ----------------
// grid = B*H*(T/64) = 1024 blocks, 256 threads (16x16 thread grid, 4x4 micro-tiles)
__global__ __launch_bounds__(256) void attn_kernel(
    const float* __restrict__ q, const float* __restrict__ kp,
    const float* __restrict__ v, float* __restrict__ attT)
{
    __shared__ __align__(16) float Qt[64][68];  // [s][t]  (Q tile transposed)
    __shared__ __align__(16) float Kt[64][68];  // [s][r]  (K' tile transposed)
    __shared__ __align__(16) float Vs[64][68];  // [r][d]
    __shared__ __align__(16) float Ps[64][68];  // [r][t]  (P transposed)

    int bid = blockIdx.x;
    int tblk = 31 - (bid & 31);        // heavy blocks first (better tail)
    int h = (bid >> 5) & 15;
    int b = bid >> 9;
    int t0 = tblk * 64;
    int tid = threadIdx.x;
    size_t base = ((size_t)(b * H_DIM + h) * T_DIM) * S_DIM;

    // stage Q tile transposed: Qt[s][t]
    for (int i = tid; i < 4096; i += 256) {
        int t = i >> 6, s = i & 63;
        Qt[s][t] = q[base + (size_t)(t0 + t) * 64 + s];
    }

    int ty = tid >> 4;   // 0..15 -> rows t = ty*4..+3
    int tx = tid & 15;   // 0..15 -> cols r/d = tx*4..+3
    float m[4], l[4], o[4][4];
#pragma unroll
    for (int i = 0; i < 4; ++i) {
        m[i] = -1e30f; l[i] = 0.f;
#pragma unroll
        for (int j = 0; j < 4; ++j) o[i][j] = 0.f;
    }

    for (int rt = 0; rt <= tblk; ++rt) {
        __syncthreads();   // prev PV readers done before overwriting K/V
        for (int i = tid; i < 4096; i += 256) {
            int r = i >> 6, s = i & 63;
            float kv = kp[base + (size_t)(rt * 64 + r) * 64 + s];
            float vv = v [base + (size_t)(rt * 64 + r) * 64 + s];
            Kt[s][r] = kv;
            Vs[r][s] = vv;
        }
        __syncthreads();

        // scores = Q @ K'^T   (4x4 per thread)
        float sacc[4][4];
#pragma unroll
        for (int i2 = 0; i2 < 4; ++i2)
#pragma unroll
            for (int j2 = 0; j2 < 4; ++j2) sacc[i2][j2] = 0.f;

#pragma unroll 4
        for (int s = 0; s < 64; ++s) {
            float4 q4 = *reinterpret_cast<const float4*>(&Qt[s][ty * 4]);
            float4 k4 = *reinterpret_cast<const float4*>(&Kt[s][tx * 4]);
            float qa[4] = {q4.x, q4.y, q4.z, q4.w};
            float ka[4] = {k4.x, k4.y, k4.z, k4.w};
#pragma unroll
            for (int i2 = 0; i2 < 4; ++i2)
#pragma unroll
                for (int j2 = 0; j2 < 4; ++j2) sacc[i2][j2] += qa[i2] * ka[j2];
        }

        // causal mask on diagonal tile
        if (rt == tblk) {
#pragma unroll
            for (int i2 = 0; i2 < 4; ++i2)
#pragma unroll
                for (int j2 = 0; j2 < 4; ++j2)
                    if (tx * 4 + j2 > ty * 4 + i2) sacc[i2][j2] = -1e30f;
        }

        // online softmax (row reduce across the 16 tx lanes)
#pragma unroll
        for (int i2 = 0; i2 < 4; ++i2) {
            float mx = fmaxf(fmaxf(sacc[i2][0], sacc[i2][1]), fmaxf(sacc[i2][2], sacc[i2][3]));
#pragma unroll
            for (int off = 1; off < 16; off <<= 1) mx = fmaxf(mx, __shfl_xor(mx, off));
            float mnew = fmaxf(m[i2], mx);
            float f = __expf(m[i2] - mnew);
            float sum = 0.f;
#pragma unroll
            for (int j2 = 0; j2 < 4; ++j2) {
                float p = __expf(sacc[i2][j2] - mnew);
                sacc[i2][j2] = p;
                sum += p;
            }
#pragma unroll
            for (int off = 1; off < 16; off <<= 1) sum += __shfl_xor(sum, off);
            l[i2] = l[i2] * f + sum;
            m[i2] = mnew;
#pragma unroll
            for (int j2 = 0; j2 < 4; ++j2) o[i2][j2] *= f;
        }

        // write P transposed, then PV
#pragma unroll
        for (int i2 = 0; i2 < 4; ++i2)
#pragma unroll
            for (int j2 = 0; j2 < 4; ++j2) Ps[tx * 4 + j2][ty * 4 + i2] = sacc[i2][j2];
        __syncthreads();

#pragma unroll 4
        for (int r = 0; r < 64; ++r) {
            float4 p4 = *reinterpret_cast<const float4*>(&Ps[r][ty * 4]);
            float4 v4 = *reinterpret_cast<const float4*>(&Vs[r][tx * 4]);
            float pa[4] = {p4.x, p4.y, p4.z, p4.w};
            float va[4] = {v4.x, v4.y, v4.z, v4.w};
#pragma unroll
            for (int i2 = 0; i2 < 4; ++i2)
#pragma unroll
                for (int j2 = 0; j2 < 4; ++j2) o[i2][j2] += pa[i2] * va[j2];
        }
    }

    // normalize + transpose in LDS (reuse Kt as [d][t]) + coalesced store to attT[b][e][t]
    __syncthreads();
#pragma unroll
    for (int i2 = 0; i2 < 4; ++i2) {
        float inv = 1.f / l[i2];
#pragma unroll
        for (int j2 = 0; j2 < 4; ++j2) Kt[tx * 4 + j2][ty * 4 + i2] = o[i2][j2] * inv;
    }
    __syncthreads();
    int dd = tid >> 2, c = tid & 3;
    float* dst = attT + ((size_t)b * E_DIM + (size_t)h * S_DIM + dd) * T_DIM + t0 + c * 16;
#pragma unroll
    for (int k4 = 0; k4 < 4; ++k4) {
        float4 val = *reinterpret_cast<const float4*>(&Kt[dd][c * 16 + k4 * 4]);
        reinterpret_cast<float4*>(dst)[k4] = val;
    }
}

// ---------------- Kernel 3: out = X2 @ Wr^T + br ----------------
// X2 = attT viewed as [B*T][E] (this IS the reference's swapaxes+reshape quirk).
__global__ __launch_bounds__(256) void final_gemm(
    const float* __restrict__ A, const float* __restrict__ Wr,
    const float* __restrict__ br, float* __restrict__ out)
{
    __shared__ __align__(16) float At[64][68];  // [k][m]
    __shared__ __align__(16) float Bt[64][68];  // [k][n]
    int nt = blockIdx.x;   // 16 tiles over N=1024
    int mt = blockIdx.y;   // 64 tiles over M=4096
    int tid = threadIdx.x;
    int ty = tid >> 4, tx = tid & 15;
    float acc[4][4];
#pragma unroll
    for (int i = 0; i < 4; ++i)
#pragma unroll
        for (int j = 0; j < 4; ++j) acc[i][j] = 0.f;

    for (int kt = 0; kt < 16; ++kt) {
        __syncthreads();
        for (int i = tid; i < 4096; i += 256) {
            int row = i >> 6, kk = i & 63;
            At[kk][row] = A[(size_t)(mt * 64 + row) * 1024 + kt * 64 + kk];
            Bt[kk][row] = Wr[(size_t)(nt * 64 + row) * 1024 + kt * 64 + kk];
        }
        __syncthreads();
#pragma unroll 4
        for (int k = 0; k < 64; ++k) {
            float4 a4 = *reinterpret_cast<const float4*>(&At[k][ty * 4]);
            float4 b4 = *reinterpret_cast<const float4*>(&Bt[k][tx * 4]);
            float aa[4] = {a4.x, a4.y, a4.z, a4.w};
            float bb[4] = {b4.x, b4.y, b4.z, b4.w};
#pragma unroll
            for (int i2 = 0; i2 < 4; ++i2)
#pragma unroll
                for (int j2 = 0; j2 < 4; ++j2) acc[i2][j2] += aa[i2] * bb[j2];
        }
    }

    int m0 = mt * 64 + ty * 4, n0 = nt * 64 + tx * 4;
    float4 bias = *reinterpret_cast<const float4*>(&br[n0]);
    float ba[4] = {bias.x, bias.y, bias.z, bias.w};
#pragma unroll
    for (int i2 = 0; i2 < 4; ++i2) {
        float4 r;
        r.x = acc[i2][0] + ba[0]; r.y = acc[i2][1] + ba[1];
        r.z = acc[i2][2] + ba[2]; r.w = acc[i2][3] + ba[3];
        *reinterpret_cast<float4*>(&out[(size_t)(m0 + i2) * 1024 + n0]) = r;
    }
}

extern "C" void kernel_launch(void* const* d_in, const int* in_sizes, int n_in,
                              void* d_out, int out_size, void* d_ws, size_t ws_size,
                              hipStream_t stream) {
    const float* x  = (const float*)d_in[0];
    const float* Wq = (const float*)d_in[1];
    const float* Wk = (const float*)d_in[2];
    const float* Wv = (const float*)d_in[3];
    const float* Er = (const float*)d_in[4];
    const float* Wr = (const float*)d_in[5];
    const float* br = (const float*)d_in[6];
    float* out = (float*)d_out;

    const size_t nQ = (size_t)B_DIM * H_DIM * T_DIM * S_DIM;  // 4,194,304
    const size_t nErT = (size_t)T_DIM * S_DIM;                // 131,072
    float* ws   = (float*)d_ws;
    float* ErT  = ws;
    float* q    = ws + nErT;
    float* kp   = q + nQ;
    float* vv   = kp + nQ;
    float* attT = vv + nQ;
    size_t need = (nErT + 4 * nQ) * sizeof(float);
    if (ws_size < need) {
        fprintf(stderr, "WS TOO SMALL: have %zu need %zu\n", ws_size, need);
        return;
    }

    er_transpose<<<512, 256, 0, stream>>>(Er, ErT);
    qkv_kernel<<<1024, 256, 0, stream>>>(x, Wq, Wk, Wv, ErT, q, kp, vv);
    attn_kernel<<<1024, 256, 0, stream>>>(q, kp, vv, attT);
    final_gemm<<<dim3(16, 64), 256, 0, stream>>>(attT, Wr, br, out);
}

// Round 2
// 247.560 us; speedup vs baseline: 3.2580x; 3.2580x over previous
//
#include <hip/hip_runtime.h>
#include <hip/hip_bf16.h>
#include <cstdio>

#define T_DIM 2048
#define B_DIM 2
#define E_DIM 1024
#define H_DIM 16
#define S_DIM 64

typedef __attribute__((ext_vector_type(4))) float f32x4;
typedef __attribute__((ext_vector_type(8))) short bf16x8;
typedef __attribute__((ext_vector_type(8))) unsigned short u16x8;
typedef __attribute__((ext_vector_type(4))) unsigned short u16x4;

#define MFMA16(a, b, c) __builtin_amdgcn_mfma_f32_16x16x32_bf16((a), (b), (c), 0, 0, 0)

__device__ __forceinline__ unsigned short f2bf(float f) {
    union { __hip_bfloat16 h; unsigned short u; } c;
    c.h = __float2bfloat16(f);
    return c.u;
}
__device__ __forceinline__ float bf2f(unsigned short u) {
    union { __hip_bfloat16 h; unsigned short u; } c;
    c.u = u;
    return __bfloat162float(c.h);
}

// ---------------- Kernel 0: transpose Er [S][T] -> ErT [T][S] ----------------
__global__ __launch_bounds__(256) void er_transpose(const float* __restrict__ Er,
                                                    float* __restrict__ ErT) {
    int idx = blockIdx.x * 256 + threadIdx.x;
    int t = idx >> 6, d = idx & 63;
    ErT[idx] = Er[d * T_DIM + t];
}

// ---------------- Kernel 0b: Wr fp32 -> bf16 ----------------
__global__ __launch_bounds__(256) void convert_bf16_4(const float* __restrict__ src,
                                                      unsigned short* __restrict__ dst) {
    int i = blockIdx.x * 256 + threadIdx.x;   // 262144 threads x 4 elems
    float4 v = reinterpret_cast<const float4*>(src)[i];
    u16x4 o;
    o[0] = f2bf(v.x); o[1] = f2bf(v.y); o[2] = f2bf(v.z); o[3] = f2bf(v.w);
    *reinterpret_cast<u16x4*>(dst + (size_t)i * 4) = o;
}

// ---------------- Kernel 1: QKV projection (fp32) + hi/lo bf16 split ----------
// k' = k/sqrt(E) + Er^T folded; v stored transposed [d][t] bf16.
__global__ __launch_bounds__(256) void qkv_kernel(
    const float* __restrict__ x, const float* __restrict__ Wq,
    const float* __restrict__ Wk, const float* __restrict__ Wv,
    const float* __restrict__ ErT,
    unsigned short* __restrict__ qh_g, unsigned short* __restrict__ ql_g,
    unsigned short* __restrict__ kh_g, unsigned short* __restrict__ kl_g,
    unsigned short* __restrict__ vT_g)
{
    __shared__ __align__(16) float xs[64][64];
    int bid = blockIdx.x;
    int tblk = bid & 31;
    int h = (bid >> 5) & 15;
    int b = bid >> 9;
    int bh = b * H_DIM + h;
    int t0 = tblk * 64;
    int tid = threadIdx.x;

    for (int i = tid; i < 1024; i += 256) {
        int t = i >> 4, c = i & 15;
        const float4* src = reinterpret_cast<const float4*>(
            x + (size_t)(t0 + t) * (B_DIM * E_DIM) + (size_t)b * E_DIM + h * S_DIM) + c;
        reinterpret_cast<float4*>(&xs[t][0])[c] = *src;
    }
    __syncthreads();

    int w = tid >> 6;
    int d = tid & 63;
    float accq[16], acck[16], accv[16];
#pragma unroll
    for (int i = 0; i < 16; ++i) { accq[i] = 0.f; acck[i] = 0.f; accv[i] = 0.f; }

    const float* wqp = Wq + (size_t)h * 4096 + (size_t)d * 64;
    const float* wkp = Wk + (size_t)h * 4096 + (size_t)d * 64;
    const float* wvp = Wv + (size_t)h * 4096 + (size_t)d * 64;

    for (int sc = 0; sc < 4; ++sc) {
        float wqr[16], wkr[16], wvr[16];
#pragma unroll
        for (int j = 0; j < 4; ++j) {
            float4 a = reinterpret_cast<const float4*>(wqp + sc * 16)[j];
            float4 c2 = reinterpret_cast<const float4*>(wkp + sc * 16)[j];
            float4 e = reinterpret_cast<const float4*>(wvp + sc * 16)[j];
            wqr[j*4+0]=a.x; wqr[j*4+1]=a.y; wqr[j*4+2]=a.z; wqr[j*4+3]=a.w;
            wkr[j*4+0]=c2.x; wkr[j*4+1]=c2.y; wkr[j*4+2]=c2.z; wkr[j*4+3]=c2.w;
            wvr[j*4+0]=e.x; wvr[j*4+1]=e.y; wvr[j*4+2]=e.z; wvr[j*4+3]=e.w;
        }
#pragma unroll
        for (int tt = 0; tt < 16; ++tt) {
            int t = w * 16 + tt;
#pragma unroll
            for (int j = 0; j < 4; ++j) {
                float4 x4 = reinterpret_cast<const float4*>(&xs[t][sc * 16])[j];
                accq[tt] += x4.x*wqr[j*4+0] + x4.y*wqr[j*4+1] + x4.z*wqr[j*4+2] + x4.w*wqr[j*4+3];
                acck[tt] += x4.x*wkr[j*4+0] + x4.y*wkr[j*4+1] + x4.z*wkr[j*4+2] + x4.w*wkr[j*4+3];
                accv[tt] += x4.x*wvr[j*4+0] + x4.y*wvr[j*4+1] + x4.z*wvr[j*4+2] + x4.w*wvr[j*4+3];
            }
        }
    }

    unsigned short vb[16];
#pragma unroll
    for (int tt = 0; tt < 16; ++tt) {
        int tg = t0 + w * 16 + tt;
        size_t ro = ((size_t)bh * T_DIM + tg) * 64 + d;
        float qv = accq[tt];
        unsigned short qh = f2bf(qv);
        qh_g[ro] = qh;
        ql_g[ro] = f2bf(qv - bf2f(qh));
        float kv = acck[tt] * 0.03125f + ErT[(size_t)tg * 64 + d];
        unsigned short kh = f2bf(kv);
        kh_g[ro] = kh;
        kl_g[ro] = f2bf(kv - bf2f(kh));
        vb[tt] = f2bf(accv[tt]);
    }
    u16x8* vdst = reinterpret_cast<u16x8*>(vT_g + ((size_t)bh * S_DIM + d) * T_DIM + t0 + w * 16);
    vdst[0] = *reinterpret_cast<u16x8*>(&vb[0]);
    vdst[1] = *reinterpret_cast<u16x8*>(&vb[8]);
}

// ---------------- Kernel 2: causal flash attention, bf16 MFMA ----------------
// LDS layout (ushort units): Kh[64][72] @0, Kl[64][72] @4608, Vt[64][72] @9216,
// P[w][16][72] @13824. Epilogue reuses [0..8703] as float[64][68].
__global__ __launch_bounds__(256) void attn_mfma(
    const unsigned short* __restrict__ qh_g, const unsigned short* __restrict__ ql_g,
    const unsigned short* __restrict__ kh_g, const unsigned short* __restrict__ kl_g,
    const unsigned short* __restrict__ vT_g, unsigned short* __restrict__ attT)
{
    __shared__ __align__(16) unsigned short sm[18432];

    int bid = blockIdx.x;
    // bid bits: [0:2]=bh low (XCD spread + L2 reuse), [3:4]=j, [5:7]=u, [8:9]=bh high.
    // tblk = g(u + 8j), g an involution making any co-resident grouping sum-constant.
    int bh = (bid & 7) | (((bid >> 8) & 3) << 3);
    int u = (bid >> 5) & 7;
    int j = (bid >> 3) & 3;
    int idx = u + 8 * j;
    int tblk = ((idx >> 3) & 1) ? ((7 - (idx & 7)) | (idx & 24)) : idx;
    int t0 = tblk * 64;

    int tid = threadIdx.x;
    int w = tid >> 6;
    int lane = tid & 63;
    int l15 = lane & 15;
    int l4 = lane >> 4;

    size_t qbase = ((size_t)bh * T_DIM) * 64;

    // Q fragments (held in registers for the whole block)
    size_t qoff = qbase + (size_t)(t0 + w * 16 + l15) * 64 + l4 * 8;
    bf16x8 qh0 = *reinterpret_cast<const bf16x8*>(qh_g + qoff);
    bf16x8 qh1 = *reinterpret_cast<const bf16x8*>(qh_g + qoff + 32);
    bf16x8 ql0 = *reinterpret_cast<const bf16x8*>(ql_g + qoff);
    bf16x8 ql1 = *reinterpret_cast<const bf16x8*>(ql_g + qoff + 32);

    f32x4 o[4];
    float m[4], l[4];
#pragma unroll
    for (int r = 0; r < 4; ++r) {
        o[r] = (f32x4){0.f, 0.f, 0.f, 0.f};
        m[r] = -1e30f;
        l[r] = 0.f;
    }

    const unsigned short* kh_base = kh_g + qbase;
    const unsigned short* kl_base = kl_g + qbase;
    const unsigned short* vt_base = vT_g + (size_t)bh * S_DIM * T_DIM;
    int pb = 13824 + w * 1152;

    for (int rt = 0; rt <= tblk; ++rt) {
        __syncthreads();
        // stage Kh, Kl (row-major [r][s]) and Vt ([d][r]) with pad-72 rows
        {
            const unsigned short* kh_src = kh_base + (size_t)(rt * 64) * 64;
            const unsigned short* kl_src = kl_base + (size_t)(rt * 64) * 64;
            const unsigned short* vt_src = vt_base + rt * 64;
            int ch = tid & 7;
#pragma unroll
            for (int k2 = 0; k2 < 6; ++k2) {
                int buf = k2 >> 1;
                int row = ((tid >> 3) + 32 * k2) & 63;
                const unsigned short* src =
                    (buf == 0) ? kh_src + row * 64 + ch * 8 :
                    (buf == 1) ? kl_src + row * 64 + ch * 8 :
                                 vt_src + (size_t)row * T_DIM + ch * 8;
                *reinterpret_cast<u16x8*>(&sm[buf * 4608 + row * 72 + ch * 8]) =
                    *reinterpret_cast<const u16x8*>(src);
            }
        }
        __syncthreads();

        // scores = Qhi*Khi + Qlo*Khi + Qhi*Klo  (fp32-grade)
        f32x4 sacc[4];
#pragma unroll
        for (int c = 0; c < 4; ++c) sacc[c] = (f32x4){0.f, 0.f, 0.f, 0.f};
#pragma unroll
        for (int c = 0; c < 4; ++c) {
#pragma unroll
            for (int kk = 0; kk < 2; ++kk) {
                int a = (c * 16 + l15) * 72 + kk * 32 + l4 * 8;
                bf16x8 bh_ = *reinterpret_cast<const bf16x8*>(&sm[a]);
                bf16x8 bl_ = *reinterpret_cast<const bf16x8*>(&sm[4608 + a]);
                bf16x8 aq = kk ? qh1 : qh0;
                bf16x8 al = kk ? ql1 : ql0;
                sacc[c] = MFMA16(aq, bh_, sacc[c]);
                sacc[c] = MFMA16(al, bh_, sacc[c]);
                sacc[c] = MFMA16(aq, bl_, sacc[c]);
            }
        }

        if (rt == tblk) {   // causal mask on the diagonal tile
            int rowb = w * 16 + l4 * 4;
#pragma unroll
            for (int c = 0; c < 4; ++c) {
                int col = c * 16 + l15;
#pragma unroll
                for (int r = 0; r < 4; ++r)
                    if (col > rowb + r) sacc[c][r] = -1e30f;
            }
        }

        // online softmax (rows live in regs across 16 lanes)
#pragma unroll
        for (int r = 0; r < 4; ++r) {
            float mx = fmaxf(fmaxf(sacc[0][r], sacc[1][r]), fmaxf(sacc[2][r], sacc[3][r]));
#pragma unroll
            for (int off = 1; off < 16; off <<= 1) mx = fmaxf(mx, __shfl_xor(mx, off));
            float mnew = fmaxf(m[r], mx);
            float f = __expf(m[r] - mnew);
            float sum = 0.f;
#pragma unroll
            for (int c = 0; c < 4; ++c) {
                float p = __expf(sacc[c][r] - mnew);
                sacc[c][r] = p;
                sum += p;
            }
#pragma unroll
            for (int off = 1; off < 16; off <<= 1) sum += __shfl_xor(sum, off);
            l[r] = l[r] * f + sum;
            m[r] = mnew;
#pragma unroll
            for (int dt = 0; dt < 4; ++dt) o[dt][r] *= f;
        }

        // P -> per-wave LDS (bf16), then PV MFMAs (same-wave, no barrier)
#pragma unroll
        for (int c = 0; c < 4; ++c)
#pragma unroll
            for (int r = 0; r < 4; ++r)
                sm[pb + (l4 * 4 + r) * 72 + c * 16 + l15] = f2bf(sacc[c][r]);

        bf16x8 pa0 = *reinterpret_cast<const bf16x8*>(&sm[pb + l15 * 72 + l4 * 8]);
        bf16x8 pa1 = *reinterpret_cast<const bf16x8*>(&sm[pb + l15 * 72 + 32 + l4 * 8]);
#pragma unroll
        for (int dt = 0; dt < 4; ++dt) {
#pragma unroll
            for (int kk = 0; kk < 2; ++kk) {
                bf16x8 vb = *reinterpret_cast<const bf16x8*>(
                    &sm[9216 + (dt * 16 + l15) * 72 + kk * 32 + l4 * 8]);
                o[dt] = MFMA16(kk ? pa1 : pa0, vb, o[dt]);
            }
        }
    }

    // epilogue: normalize, transpose via LDS, store attT[b][e][t] bf16
    __syncthreads();
    float inv[4];
#pragma unroll
    for (int r = 0; r < 4; ++r) inv[r] = 1.f / l[r];
    float* tr = reinterpret_cast<float*>(sm);   // [64][68]
#pragma unroll
    for (int dt = 0; dt < 4; ++dt)
#pragma unroll
        for (int r = 0; r < 4; ++r)
            tr[(dt * 16 + l15) * 68 + w * 16 + l4 * 4 + r] = o[dt][r] * inv[r];
    __syncthreads();

    int dd = tid >> 2, cc = tid & 3;
    unsigned short tmp[16];
#pragma unroll
    for (int q2 = 0; q2 < 16; ++q2) tmp[q2] = f2bf(tr[dd * 68 + cc * 16 + q2]);
    u16x8* dst = reinterpret_cast<u16x8*>(attT + ((size_t)bh * S_DIM + dd) * T_DIM + t0 + cc * 16);
    dst[0] = *reinterpret_cast<u16x8*>(&tmp[0]);
    dst[1] = *reinterpret_cast<u16x8*>(&tmp[8]);
}

// ---------------- Kernel 3: out = attT(as [4096][1024]) @ Wr^T + br, bf16 MFMA --
__global__ __launch_bounds__(256) void final_gemm_mfma(
    const unsigned short* __restrict__ A, const unsigned short* __restrict__ Bw,
    const float* __restrict__ br, float* __restrict__ out)
{
    __shared__ __align__(16) unsigned short gsm[9216];  // Asub[64][72], Bsub[64][72]
    int nt = blockIdx.x;
    int mt = blockIdx.y;
    int tid = threadIdx.x;
    int w = tid >> 6;
    int lane = tid & 63;
    int l15 = lane & 15;
    int l4 = lane >> 4;

    f32x4 acc[4];
#pragma unroll
    for (int n = 0; n < 4; ++n) acc[n] = (f32x4){0.f, 0.f, 0.f, 0.f};

    for (int kt = 0; kt < 16; ++kt) {
        __syncthreads();
        int ch = tid & 7;
#pragma unroll
        for (int k2 = 0; k2 < 4; ++k2) {
            int buf = k2 >> 1;
            int row = ((tid >> 3) + 32 * k2) & 63;
            const unsigned short* src = buf
                ? Bw + (size_t)(nt * 64 + row) * 1024 + kt * 64 + ch * 8
                : A  + (size_t)(mt * 64 + row) * 1024 + kt * 64 + ch * 8;
            *reinterpret_cast<u16x8*>(&gsm[buf * 4608 + row * 72 + ch * 8]) =
                *reinterpret_cast<const u16x8*>(src);
        }
        __syncthreads();

        bf16x8 a0 = *reinterpret_cast<const bf16x8*>(&gsm[(w * 16 + l15) * 72 + l4 * 8]);
        bf16x8 a1 = *reinterpret_cast<const bf16x8*>(&gsm[(w * 16 + l15) * 72 + 32 + l4 * 8]);
#pragma unroll
        for (int n = 0; n < 4; ++n) {
            bf16x8 b0 = *reinterpret_cast<const bf16x8*>(&gsm[4608 + (n * 16 + l15) * 72 + l4 * 8]);
            bf16x8 b1 = *reinterpret_cast<const bf16x8*>(&gsm[4608 + (n * 16 + l15) * 72 + 32 + l4 * 8]);
            acc[n] = MFMA16(a0, b0, acc[n]);
            acc[n] = MFMA16(a1, b1, acc[n]);
        }
    }

#pragma unroll
    for (int n = 0; n < 4; ++n) {
        int col = nt * 64 + n * 16 + l15;
        float bias = br[col];
#pragma unroll
        for (int r = 0; r < 4; ++r) {
            int row = mt * 64 + w * 16 + l4 * 4 + r;
            out[(size_t)row * 1024 + col] = acc[n][r] + bias;
        }
    }
}

extern "C" void kernel_launch(void* const* d_in, const int* in_sizes, int n_in,
                              void* d_out, int out_size, void* d_ws, size_t ws_size,
                              hipStream_t stream) {
    const float* x  = (const float*)d_in[0];
    const float* Wq = (const float*)d_in[1];
    const float* Wk = (const float*)d_in[2];
    const float* Wv = (const float*)d_in[3];
    const float* Er = (const float*)d_in[4];
    const float* Wr = (const float*)d_in[5];
    const float* br = (const float*)d_in[6];
    float* out = (float*)d_out;

    const size_t nQ = (size_t)B_DIM * H_DIM * T_DIM * S_DIM;   // 4,194,304 elems
    char* p = (char*)d_ws;
    float* ErT = (float*)p;                 p += (size_t)T_DIM * S_DIM * 4;  // 524288 B
    unsigned short* qh = (unsigned short*)p; p += nQ * 2;
    unsigned short* ql = (unsigned short*)p; p += nQ * 2;
    unsigned short* kh = (unsigned short*)p; p += nQ * 2;
    unsigned short* kl = (unsigned short*)p; p += nQ * 2;
    unsigned short* vT = (unsigned short*)p; p += nQ * 2;
    unsigned short* attT = (unsigned short*)p; p += nQ * 2;
    unsigned short* wrb = (unsigned short*)p; p += (size_t)E_DIM * E_DIM * 2;
    size_t need = (size_t)(p - (char*)d_ws);
    if (ws_size < need) {
        fprintf(stderr, "WS TOO SMALL: have %zu need %zu\n", ws_size, need);
        return;
    }

    er_transpose<<<512, 256, 0, stream>>>(Er, ErT);
    convert_bf16_4<<<1024, 256, 0, stream>>>(Wr, wrb);
    qkv_kernel<<<1024, 256, 0, stream>>>(x, Wq, Wk, Wv, ErT, qh, ql, kh, kl, vT);
    attn_mfma<<<1024, 256, 0, stream>>>(qh, ql, kh, kl, vT, attT);
    final_gemm_mfma<<<dim3(16, 64), 256, 0, stream>>>(attT, wrb, br, out);
}

// Round 4
// 161.053 us; speedup vs baseline: 5.0080x; 1.5371x over previous
//
#include <hip/hip_runtime.h>
#include <hip/hip_bf16.h>
#include <cstdio>

#define T_DIM 2048
#define B_DIM 2
#define E_DIM 1024
#define H_DIM 16
#define S_DIM 64
#define LOG2E 1.44269504088896340736f

typedef __attribute__((ext_vector_type(4))) float f32x4;
typedef __attribute__((ext_vector_type(16))) float f32x16;
typedef __attribute__((ext_vector_type(8))) short bf16x8;
typedef __attribute__((ext_vector_type(8))) unsigned short u16x8;
typedef __attribute__((ext_vector_type(4))) unsigned short u16x4;

#define MFMA16(a,b,c) __builtin_amdgcn_mfma_f32_16x16x32_bf16((a),(b),(c),0,0,0)
#define MFMA32(a,b,c) __builtin_amdgcn_mfma_f32_32x32x16_bf16((a),(b),(c),0,0,0)

__device__ __forceinline__ unsigned short f2bf(float f) {
    union { __hip_bfloat16 h; unsigned short u; } c;
    c.h = __float2bfloat16(f);
    return c.u;
}
__device__ __forceinline__ float bf2f(unsigned short u) {
    union { __hip_bfloat16 h; unsigned short u; } c;
    c.u = u;
    return __bfloat162float(c.h);
}
__device__ __forceinline__ void gload16(const void* g, void* l) {
    __builtin_amdgcn_global_load_lds(
        (const __attribute__((address_space(1))) unsigned int*)g,
        (__attribute__((address_space(3))) unsigned int*)l, 16, 0, 0);
}
__device__ __forceinline__ f32x16 zero16() {
    f32x16 v;
#pragma unroll
    for (int i = 0; i < 16; ++i) v[i] = 0.f;
    return v;
}

// ---------------- Kernel 0: transpose Er [S][T] -> ErT [T][S] ----------------
__global__ __launch_bounds__(256) void er_transpose(const float* __restrict__ Er,
                                                    float* __restrict__ ErT) {
    int idx = blockIdx.x * 256 + threadIdx.x;
    int t = idx >> 6, d = idx & 63;
    ErT[idx] = Er[d * T_DIM + t];
}

// ---------------- Kernel 0b: Wr fp32 -> bf16 ----------------
__global__ __launch_bounds__(256) void convert_bf16_4(const float* __restrict__ src,
                                                      unsigned short* __restrict__ dst) {
    int i = blockIdx.x * 256 + threadIdx.x;
    float4 v = reinterpret_cast<const float4*>(src)[i];
    u16x4 o;
    o[0] = f2bf(v.x); o[1] = f2bf(v.y); o[2] = f2bf(v.z); o[3] = f2bf(v.w);
    *reinterpret_cast<u16x4*>(dst + (size_t)i * 4) = o;
}

// ---------------- Kernel 1: QKV projection (fp32) -------------------------
// q -> hi/lo bf16; k' = log2e*(k/sqrt(E) + Er^T) single bf16; v transposed [d][t].
__global__ __launch_bounds__(256) void qkv_kernel(
    const float* __restrict__ x, const float* __restrict__ Wq,
    const float* __restrict__ Wk, const float* __restrict__ Wv,
    const float* __restrict__ ErT,
    unsigned short* __restrict__ qh_g, unsigned short* __restrict__ ql_g,
    unsigned short* __restrict__ kh_g, unsigned short* __restrict__ vT_g)
{
    __shared__ __align__(16) float xs[64][64];
    int bid = blockIdx.x;
    int tblk = bid & 31;
    int h = (bid >> 5) & 15;
    int b = bid >> 9;
    int bh = b * H_DIM + h;
    int t0 = tblk * 64;
    int tid = threadIdx.x;

    for (int i = tid; i < 1024; i += 256) {
        int t = i >> 4, c = i & 15;
        const float4* src = reinterpret_cast<const float4*>(
            x + (size_t)(t0 + t) * (B_DIM * E_DIM) + (size_t)b * E_DIM + h * S_DIM) + c;
        reinterpret_cast<float4*>(&xs[t][0])[c] = *src;
    }
    __syncthreads();

    int w = tid >> 6;
    int d = tid & 63;
    float accq[16], acck[16], accv[16];
#pragma unroll
    for (int i = 0; i < 16; ++i) { accq[i] = 0.f; acck[i] = 0.f; accv[i] = 0.f; }

    const float* wqp = Wq + (size_t)h * 4096 + (size_t)d * 64;
    const float* wkp = Wk + (size_t)h * 4096 + (size_t)d * 64;
    const float* wvp = Wv + (size_t)h * 4096 + (size_t)d * 64;

    for (int sc = 0; sc < 4; ++sc) {
        float wqr[16], wkr[16], wvr[16];
#pragma unroll
        for (int j = 0; j < 4; ++j) {
            float4 a = reinterpret_cast<const float4*>(wqp + sc * 16)[j];
            float4 c2 = reinterpret_cast<const float4*>(wkp + sc * 16)[j];
            float4 e = reinterpret_cast<const float4*>(wvp + sc * 16)[j];
            wqr[j*4+0]=a.x; wqr[j*4+1]=a.y; wqr[j*4+2]=a.z; wqr[j*4+3]=a.w;
            wkr[j*4+0]=c2.x; wkr[j*4+1]=c2.y; wkr[j*4+2]=c2.z; wkr[j*4+3]=c2.w;
            wvr[j*4+0]=e.x; wvr[j*4+1]=e.y; wvr[j*4+2]=e.z; wvr[j*4+3]=e.w;
        }
#pragma unroll
        for (int tt = 0; tt < 16; ++tt) {
            int t = w * 16 + tt;
#pragma unroll
            for (int j = 0; j < 4; ++j) {
                float4 x4 = reinterpret_cast<const float4*>(&xs[t][sc * 16])[j];
                accq[tt] += x4.x*wqr[j*4+0] + x4.y*wqr[j*4+1] + x4.z*wqr[j*4+2] + x4.w*wqr[j*4+3];
                acck[tt] += x4.x*wkr[j*4+0] + x4.y*wkr[j*4+1] + x4.z*wkr[j*4+2] + x4.w*wkr[j*4+3];
                accv[tt] += x4.x*wvr[j*4+0] + x4.y*wvr[j*4+1] + x4.z*wvr[j*4+2] + x4.w*wvr[j*4+3];
            }
        }
    }

    unsigned short vb[16];
#pragma unroll
    for (int tt = 0; tt < 16; ++tt) {
        int tg = t0 + w * 16 + tt;
        size_t ro = ((size_t)bh * T_DIM + tg) * 64 + d;
        float qv = accq[tt];
        unsigned short qh = f2bf(qv);
        qh_g[ro] = qh;
        ql_g[ro] = f2bf(qv - bf2f(qh));
        // k' = log2e * (k/sqrt(E) + Er[d][t])  (folds srel, score scale, exp2 base)
        kh_g[ro] = f2bf((acck[tt] * 0.03125f + ErT[(size_t)tg * 64 + d]) * LOG2E);
        vb[tt] = f2bf(accv[tt]);
    }
    u16x8* vdst = reinterpret_cast<u16x8*>(vT_g + ((size_t)bh * S_DIM + d) * T_DIM + t0 + w * 16);
    vdst[0] = *reinterpret_cast<u16x8*>(&vb[0]);
    vdst[1] = *reinterpret_cast<u16x8*>(&vb[8]);
}

// ---------------- Kernel 2: causal flash attention, 32x32x16 MFMA ------------
// Block: 128 q-rows, 4 waves (wave = 32 q). K-steps of 128.
// QK^T swapped (S^T = K x Q): lane owns ONE q-row -> lane-local softmax.
// PV as O^T = V^T x P^T: output fragment col = q (lane-local) so the online
// rescale is per-lane-correct; regs = d-rows.  P stays in registers via
// cvt_pk_bf16 + permlane32_swap.
// LDS: KH [128 rows][64 d] bf16 (16KB, xor-swizzled slots),
//      VT [64 d][128 t] bf16 (16KB, swizzled); epilogue reuses as OT f32[64][132].
__global__ __launch_bounds__(256) void attn_mfma32(
    const unsigned short* __restrict__ qh_g, const unsigned short* __restrict__ ql_g,
    const unsigned short* __restrict__ kh_g, const unsigned short* __restrict__ vT_g,
    unsigned short* __restrict__ attT)
{
    __shared__ __align__(16) unsigned char smem[33792];
    unsigned short* KH = (unsigned short*)smem;            // 16KB @0
    unsigned short* VT = (unsigned short*)(smem + 16384);  // 16KB @16K
    float* OT = (float*)smem;                              // [64][132] epilogue reuse

    int bid = blockIdx.x;
    int bh = bid & 31;            // all 16 blocks of a head -> same XCD (L2 reuse)
    int u = bid >> 5;
    int qt = (u < 8) ? (15 - u) : (u - 8);  // co-CU pair (u,u+8) sums to 17 steps

    int tid = threadIdx.x;
    int w = tid >> 6;
    int lane = tid & 63;
    int l31 = lane & 31;
    int hs = lane >> 5;

    size_t base = (size_t)bh * T_DIM * 64;

    // Q B-frags in registers for the whole block: q-col t = qt*128+w*32+l31
    bf16x8 qBh[4], qBl[4];
    {
        size_t qoff = base + (size_t)(qt * 128 + w * 32 + l31) * 64 + hs * 8;
#pragma unroll
        for (int st = 0; st < 4; ++st) {
            qBh[st] = *reinterpret_cast<const bf16x8*>(qh_g + qoff + st * 16);
            qBl[st] = *reinterpret_cast<const bf16x8*>(ql_g + qoff + st * 16);
        }
    }

    f32x16 oacc0 = zero16(), oacc1 = zero16();   // O^T frags: col=q(lane), regs=d
    float m = -1e30f, lsum = 0.f;

    int r8 = lane >> 3, c7 = lane & 7;
    int csrcK = c7 ^ r8;                 // KH source swizzle (row&7 == r8)
    int d4 = lane >> 4, s15 = lane & 15;

    for (int rt = 0; rt <= qt; ++rt) {
        __syncthreads();
        // ---- stage KH[128][64] + VT[64][128], swizzled content, linear dest ----
#pragma unroll
        for (int ci = 0; ci < 4; ++ci) {
            int chunk = w * 4 + ci;
            int row = chunk * 8 + r8;
            gload16(kh_g + base + (size_t)(rt * 128 + row) * 64 + csrcK * 8,
                    (char*)KH + chunk * 1024 + lane * 16);
        }
#pragma unroll
        for (int ci = 0; ci < 4; ++ci) {
            int chunk = w * 4 + ci;
            int d = chunk * 4 + d4;
            int cdat = (s15 & 8) | ((s15 ^ d) & 7);
            gload16(vT_g + base + (size_t)d * T_DIM + rt * 128 + cdat * 8,
                    (char*)VT + chunk * 1024 + lane * 16);
        }
        __syncthreads();

        int kmax = (rt == qt) ? w : 3;
        for (int kt = 0; kt <= kmax; ++kt) {
            // ---- S^T = K' x Q (hi + lo), 32x32x16: D[krow][q], col=q=l31 ----
            int krow = kt * 32 + l31;
            f32x16 s = zero16();
#pragma unroll
            for (int st = 0; st < 4; ++st) {
                int slot = (st * 2 + hs) ^ (krow & 7);
                bf16x8 kf = *reinterpret_cast<const bf16x8*>((char*)KH + krow * 128 + slot * 16);
                s = MFMA32(kf, qBh[st], s);
                s = MFMA32(kf, qBl[st], s);
            }
            if (rt == qt && kt == w) {
#pragma unroll
                for (int r = 0; r < 16; ++r) {
                    int rowp = (r & 3) + 8 * (r >> 2) + 4 * hs;
                    if (rowp > l31) s[r] = -1e30f;   // mask krow > q
                }
            }
            // ---- online softmax (lane-local q-row; cross only lane^32) ----
            float pmax = s[0];
#pragma unroll
            for (int r = 1; r < 16; ++r) pmax = fmaxf(pmax, s[r]);
            pmax = fmaxf(pmax, __shfl_xor(pmax, 32));
            if (__ballot(pmax > m)) {
                float mn = fmaxf(m, pmax);
                float sc = __builtin_amdgcn_exp2f(m - mn);
                m = mn; lsum *= sc;
#pragma unroll
                for (int r = 0; r < 16; ++r) { oacc0[r] *= sc; oacc1[r] *= sc; }
            }
            float p[16], psum = 0.f;
#pragma unroll
            for (int r = 0; r < 16; ++r) {
                p[r] = __builtin_amdgcn_exp2f(s[r] - m);
                psum += p[r];
            }
            lsum += psum + __shfl_xor(psum, 32);

            // ---- P -> bf16 PV frags in-register (cvt_pk + permlane32_swap) ----
            // After swaps: wp[h*4+j] lane(l31,hs) = P[q=l31][kt*32+h*16+hs*8+2j..+1]
            unsigned int wp[8];
#pragma unroll
            for (int q2 = 0; q2 < 2; ++q2) {
                int o = q2 * 8, d2 = q2 * 4;
                asm("v_cvt_pk_bf16_f32 %0, %1, %2" : "=v"(wp[d2+0]) : "v"(p[o+0]), "v"(p[o+1]));
                asm("v_cvt_pk_bf16_f32 %0, %1, %2" : "=v"(wp[d2+1]) : "v"(p[o+2]), "v"(p[o+3]));
                asm("v_cvt_pk_bf16_f32 %0, %1, %2" : "=v"(wp[d2+2]) : "v"(p[o+4]), "v"(p[o+5]));
                asm("v_cvt_pk_bf16_f32 %0, %1, %2" : "=v"(wp[d2+3]) : "v"(p[o+6]), "v"(p[o+7]));
                asm("v_permlane32_swap_b32 %0, %1" : "+v"(wp[d2+0]), "+v"(wp[d2+2]));
                asm("v_permlane32_swap_b32 %0, %1" : "+v"(wp[d2+1]), "+v"(wp[d2+3]));
            }
            // ---- PV: O^T += V^T x P^T  (A=V^T rows=d, B=P^T cols=q) ----
#pragma unroll
            for (int half = 0; half < 2; ++half) {
                union { unsigned int u[4]; bf16x8 v; } pa;
                pa.u[0] = wp[half*4+0]; pa.u[1] = wp[half*4+1];
                pa.u[2] = wp[half*4+2]; pa.u[3] = wp[half*4+3];
#pragma unroll
                for (int dt = 0; dt < 2; ++dt) {
                    int d = dt * 32 + l31;
                    int c = kt * 4 + half * 2 + hs;
                    int slot = (c & 8) | ((c ^ d) & 7);
                    bf16x8 vb = *reinterpret_cast<const bf16x8*>((char*)VT + d * 256 + slot * 16);
                    if (dt == 0) oacc0 = MFMA32(vb, pa.v, oacc0);
                    else         oacc1 = MFMA32(vb, pa.v, oacc1);
                }
            }
        }
    }

    // ---- epilogue: normalize (lane-local), stage OT[d][q], store attT bf16 ----
    float inv = 1.f / lsum;
    __syncthreads();   // all K/V LDS reads done before OT overwrites
#pragma unroll
    for (int r = 0; r < 16; ++r) {
        int rowp = (r & 3) + 8 * (r >> 2) + 4 * hs;   // d-row within 32
        OT[(rowp)      * 132 + w * 32 + l31] = oacc0[r] * inv;
        OT[(32 + rowp) * 132 + w * 32 + l31] = oacc1[r] * inv;
    }
    __syncthreads();
    {
        int d = tid >> 2, qb = tid & 3;
        unsigned short tmp[32];
#pragma unroll
        for (int i = 0; i < 8; ++i) {
            f32x4 v = *reinterpret_cast<const f32x4*>(&OT[d * 132 + qb * 32 + i * 4]);
            tmp[i*4+0] = f2bf(v[0]); tmp[i*4+1] = f2bf(v[1]);
            tmp[i*4+2] = f2bf(v[2]); tmp[i*4+3] = f2bf(v[3]);
        }
        unsigned short* dst = attT + ((size_t)bh * 64 + d) * T_DIM + qt * 128 + qb * 32;
        *reinterpret_cast<u16x8*>(dst)      = *reinterpret_cast<u16x8*>(&tmp[0]);
        *reinterpret_cast<u16x8*>(dst + 8)  = *reinterpret_cast<u16x8*>(&tmp[8]);
        *reinterpret_cast<u16x8*>(dst + 16) = *reinterpret_cast<u16x8*>(&tmp[16]);
        *reinterpret_cast<u16x8*>(dst + 24) = *reinterpret_cast<u16x8*>(&tmp[24]);
    }
}

// ---------------- Kernel 3: out = attT(as [4096][1024]) @ Wr^T + br ----------
__global__ __launch_bounds__(256) void final_gemm_mfma(
    const unsigned short* __restrict__ A, const unsigned short* __restrict__ Bw,
    const float* __restrict__ br, float* __restrict__ out)
{
    __shared__ __align__(16) unsigned short gsm[9216];
    int nt = blockIdx.x;
    int mt = blockIdx.y;
    int tid = threadIdx.x;
    int w = tid >> 6;
    int lane = tid & 63;
    int l15 = lane & 15;
    int l4 = lane >> 4;

    f32x4 acc[4];
#pragma unroll
    for (int n = 0; n < 4; ++n) acc[n] = (f32x4){0.f, 0.f, 0.f, 0.f};

    for (int kt = 0; kt < 16; ++kt) {
        __syncthreads();
        int ch = tid & 7;
#pragma unroll
        for (int k2 = 0; k2 < 4; ++k2) {
            int buf = k2 >> 1;
            int row = ((tid >> 3) + 32 * k2) & 63;
            const unsigned short* src = buf
                ? Bw + (size_t)(nt * 64 + row) * 1024 + kt * 64 + ch * 8
                : A  + (size_t)(mt * 64 + row) * 1024 + kt * 64 + ch * 8;
            *reinterpret_cast<u16x8*>(&gsm[buf * 4608 + row * 72 + ch * 8]) =
                *reinterpret_cast<const u16x8*>(src);
        }
        __syncthreads();

        bf16x8 a0 = *reinterpret_cast<const bf16x8*>(&gsm[(w * 16 + l15) * 72 + l4 * 8]);
        bf16x8 a1 = *reinterpret_cast<const bf16x8*>(&gsm[(w * 16 + l15) * 72 + 32 + l4 * 8]);
#pragma unroll
        for (int n = 0; n < 4; ++n) {
            bf16x8 b0 = *reinterpret_cast<const bf16x8*>(&gsm[4608 + (n * 16 + l15) * 72 + l4 * 8]);
            bf16x8 b1 = *reinterpret_cast<const bf16x8*>(&gsm[4608 + (n * 16 + l15) * 72 + 32 + l4 * 8]);
            acc[n] = MFMA16(a0, b0, acc[n]);
            acc[n] = MFMA16(a1, b1, acc[n]);
        }
    }

#pragma unroll
    for (int n = 0; n < 4; ++n) {
        int col = nt * 64 + n * 16 + l15;
        float bias = br[col];
#pragma unroll
        for (int r = 0; r < 4; ++r) {
            int row = mt * 64 + w * 16 + l4 * 4 + r;
            out[(size_t)row * 1024 + col] = acc[n][r] + bias;
        }
    }
}

extern "C" void kernel_launch(void* const* d_in, const int* in_sizes, int n_in,
                              void* d_out, int out_size, void* d_ws, size_t ws_size,
                              hipStream_t stream) {
    const float* x  = (const float*)d_in[0];
    const float* Wq = (const float*)d_in[1];
    const float* Wk = (const float*)d_in[2];
    const float* Wv = (const float*)d_in[3];
    const float* Er = (const float*)d_in[4];
    const float* Wr = (const float*)d_in[5];
    const float* br = (const float*)d_in[6];
    float* out = (float*)d_out;

    const size_t nQ = (size_t)B_DIM * H_DIM * T_DIM * S_DIM;   // 4,194,304
    char* p = (char*)d_ws;
    float* ErT = (float*)p;                  p += (size_t)T_DIM * S_DIM * 4;
    unsigned short* qh = (unsigned short*)p;  p += nQ * 2;
    unsigned short* ql = (unsigned short*)p;  p += nQ * 2;
    unsigned short* kh = (unsigned short*)p;  p += nQ * 2;
    unsigned short* vT = (unsigned short*)p;  p += nQ * 2;
    unsigned short* attT = (unsigned short*)p; p += nQ * 2;
    unsigned short* wrb = (unsigned short*)p;  p += (size_t)E_DIM * E_DIM * 2;
    size_t need = (size_t)(p - (char*)d_ws);
    if (ws_size < need) {
        fprintf(stderr, "WS TOO SMALL: have %zu need %zu\n", ws_size, need);
        return;
    }

    er_transpose<<<512, 256, 0, stream>>>(Er, ErT);
    convert_bf16_4<<<1024, 256, 0, stream>>>(Wr, wrb);
    qkv_kernel<<<1024, 256, 0, stream>>>(x, Wq, Wk, Wv, ErT, qh, ql, kh, vT);
    attn_mfma32<<<512, 256, 0, stream>>>(qh, ql, kh, vT, attT);
    final_gemm_mfma<<<dim3(16, 64), 256, 0, stream>>>(attT, wrb, br, out);
}

// Round 5
// 111.695 us; speedup vs baseline: 7.2211x; 1.4419x over previous
//
#include <hip/hip_runtime.h>
#include <hip/hip_bf16.h>
#include <cstdio>

#define T_DIM 2048
#define B_DIM 2
#define E_DIM 1024
#define H_DIM 16
#define S_DIM 64
#define LOG2E 1.44269504088896340736f

typedef __attribute__((ext_vector_type(4))) float f32x4;
typedef __attribute__((ext_vector_type(16))) float f32x16;
typedef __attribute__((ext_vector_type(8))) short bf16x8;
typedef __attribute__((ext_vector_type(8))) unsigned short u16x8;
typedef __attribute__((ext_vector_type(4))) unsigned short u16x4;

#define MFMA16(a,b,c) __builtin_amdgcn_mfma_f32_16x16x32_bf16((a),(b),(c),0,0,0)
#define MFMA32(a,b,c) __builtin_amdgcn_mfma_f32_32x32x16_bf16((a),(b),(c),0,0,0)

__device__ __forceinline__ unsigned short f2bf(float f) {
    union { __hip_bfloat16 h; unsigned short u; } c;
    c.h = __float2bfloat16(f);
    return c.u;
}
__device__ __forceinline__ float bf2f(unsigned short u) {
    union { __hip_bfloat16 h; unsigned short u; } c;
    c.u = u;
    return __bfloat162float(c.h);
}
__device__ __forceinline__ void gload16(const void* g, void* l) {
    __builtin_amdgcn_global_load_lds(
        (const __attribute__((address_space(1))) unsigned int*)g,
        (__attribute__((address_space(3))) unsigned int*)l, 16, 0, 0);
}
__device__ __forceinline__ f32x16 zero16() {
    f32x16 v;
#pragma unroll
    for (int i = 0; i < 16; ++i) v[i] = 0.f;
    return v;
}

// ---------------- Kernel 0: transpose Er [S][T] -> ErT [T][S] ----------------
__global__ __launch_bounds__(256) void er_transpose(const float* __restrict__ Er,
                                                    float* __restrict__ ErT) {
    int idx = blockIdx.x * 256 + threadIdx.x;
    int t = idx >> 6, d = idx & 63;
    ErT[idx] = Er[d * T_DIM + t];
}

// ---------------- Kernel 0b: Wr fp32 -> bf16 ----------------
__global__ __launch_bounds__(256) void convert_bf16_4(const float* __restrict__ src,
                                                      unsigned short* __restrict__ dst) {
    int i = blockIdx.x * 256 + threadIdx.x;
    float4 v = reinterpret_cast<const float4*>(src)[i];
    u16x4 o;
    o[0] = f2bf(v.x); o[1] = f2bf(v.y); o[2] = f2bf(v.z); o[3] = f2bf(v.w);
    *reinterpret_cast<u16x4*>(dst + (size_t)i * 4) = o;
}

// ---------------- Kernel 0c: Wq/Wk/Wv fp32 -> hi/lo bf16 split ----------------
// Layout: [mat(3)][h][d][s] flat (65536 elems per mat).
__global__ __launch_bounds__(256) void split_w(
    const float* __restrict__ Wq, const float* __restrict__ Wk,
    const float* __restrict__ Wv,
    unsigned short* __restrict__ whi, unsigned short* __restrict__ wlo) {
    int i = blockIdx.x * 256 + threadIdx.x;   // 196608 total
    const float* src = (i < 65536) ? Wq : ((i < 131072) ? Wk : Wv);
    float v = src[i & 65535];
    unsigned short h = f2bf(v);
    whi[i] = h;
    wlo[i] = f2bf(v - bf2f(h));
}

// ---------------- Kernel 1: QKV projection via hi/lo bf16 MFMA ----------------
// fp32-grade: x = xh+xl, W = wh+wl; acc = xh*wh + xl*wh + xh*wl (3 MFMAs/pair).
// One wave per block; 32 t-rows x 32 d-cols (dg half) x 3 matrices.
// A-frag and B-frag of 32x32x16 share the lane layout (row/col = lane&31,
// k = (lane>>5)*8+j), so x-frags serve as A for q,k and as B for v = W*x^T.
__global__ __launch_bounds__(64) void qkv_mfma(
    const float* __restrict__ x, const unsigned short* __restrict__ whi,
    const unsigned short* __restrict__ wlo, const float* __restrict__ ErT,
    unsigned short* __restrict__ qh_g, unsigned short* __restrict__ ql_g,
    unsigned short* __restrict__ kh_g, unsigned short* __restrict__ vT_g)
{
    int bid = blockIdx.x;
    int dg = bid & 1;
    int tt = (bid >> 1) & 63;
    int h  = (bid >> 7) & 15;
    int b  = bid >> 11;
    int bh = b * H_DIM + h;
    int t0 = tt * 32;
    int lane = threadIdx.x;
    int l31 = lane & 31, hs = lane >> 5;

    // x row fragments, split hi/lo (lane: row t0+l31, k-chunk hs*8)
    bf16x8 xh[4], xl[4];
    const float* xrow = x + (size_t)(t0 + l31) * (B_DIM * E_DIM) + (size_t)b * E_DIM + h * 64;
#pragma unroll
    for (int ks = 0; ks < 4; ++ks) {
        float vv[8];
        *reinterpret_cast<float4*>(&vv[0]) = *reinterpret_cast<const float4*>(xrow + ks * 16 + hs * 8);
        *reinterpret_cast<float4*>(&vv[4]) = *reinterpret_cast<const float4*>(xrow + ks * 16 + hs * 8 + 4);
        unsigned short hh[8], ll[8];
#pragma unroll
        for (int j = 0; j < 8; ++j) {
            hh[j] = f2bf(vv[j]);
            ll[j] = f2bf(vv[j] - bf2f(hh[j]));
        }
        xh[ks] = *reinterpret_cast<bf16x8*>(hh);
        xl[ks] = *reinterpret_cast<bf16x8*>(ll);
    }

    f32x16 aq = zero16(), ak = zero16(), av = zero16();
    size_t wofs = (size_t)h * 4096 + (size_t)(dg * 32 + l31) * 64 + hs * 8;
    const unsigned short* whp = whi + wofs;
    const unsigned short* wlp = wlo + wofs;
#pragma unroll
    for (int ks = 0; ks < 4; ++ks) {
        bf16x8 qwh = *reinterpret_cast<const bf16x8*>(whp + ks * 16);
        bf16x8 qwl = *reinterpret_cast<const bf16x8*>(wlp + ks * 16);
        bf16x8 kwh = *reinterpret_cast<const bf16x8*>(whp + 65536 + ks * 16);
        bf16x8 kwl = *reinterpret_cast<const bf16x8*>(wlp + 65536 + ks * 16);
        bf16x8 vwh = *reinterpret_cast<const bf16x8*>(whp + 131072 + ks * 16);
        bf16x8 vwl = *reinterpret_cast<const bf16x8*>(wlp + 131072 + ks * 16);
        aq = MFMA32(xh[ks], qwh, aq);
        aq = MFMA32(xl[ks], qwh, aq);
        aq = MFMA32(xh[ks], qwl, aq);
        ak = MFMA32(xh[ks], kwh, ak);
        ak = MFMA32(xl[ks], kwh, ak);
        ak = MFMA32(xh[ks], kwl, ak);
        av = MFMA32(vwh, xh[ks], av);   // v computed transposed: D = W*x^T
        av = MFMA32(vwh, xl[ks], av);
        av = MFMA32(vwl, xh[ks], av);
    }

    // epilogue: q hi/lo, k' (srel+scale+log2e folded), vT
    size_t rowbase = (size_t)bh * T_DIM * 64;
#pragma unroll
    for (int r = 0; r < 16; ++r) {
        int rowp = (r & 3) + 8 * (r >> 2) + 4 * hs;
        int t = t0 + rowp;
        int d = dg * 32 + l31;
        size_t ro = rowbase + (size_t)t * 64 + d;
        float qv = aq[r];
        unsigned short qhi = f2bf(qv);
        qh_g[ro] = qhi;
        ql_g[ro] = f2bf(qv - bf2f(qhi));
        float kv = (ak[r] * 0.03125f + ErT[t * 64 + d]) * LOG2E;
        kh_g[ro] = f2bf(kv);
        // av frag: col = t (t0+l31), row = d (dg*32+rowp)
        vT_g[((size_t)bh * 64 + dg * 32 + rowp) * T_DIM + t0 + l31] = f2bf(av[r]);
    }
}

// ---------------- Kernel 2: causal flash attention, 32x32x16 MFMA ------------
// Block: 128 q-rows, 4 waves. K-steps of 128, double-buffered LDS with
// prefetch-before-compute (2-phase): stage(t+1) issues, compute(t) hides it,
// end-of-iter __syncthreads drains. Swapped QK^T -> lane-local softmax;
// PV as O^T = V^T x P^T (col = q = lane); P in-register via cvt_pk+permlane.
// LDS: 2 x { KH[128][64] @+0, VT[64][128] @+16K } = 64KB; epilogue reuses.
__global__ __launch_bounds__(256) void attn_mfma32(
    const unsigned short* __restrict__ qh_g, const unsigned short* __restrict__ ql_g,
    const unsigned short* __restrict__ kh_g, const unsigned short* __restrict__ vT_g,
    unsigned short* __restrict__ attT)
{
    __shared__ __align__(16) unsigned char smem[65536];
    float* OT = (float*)smem;   // [64][132] epilogue reuse

    int bid = blockIdx.x;
    int bh = bid & 31;            // all 16 blocks of a head -> same XCD (L2 reuse)
    int u = bid >> 5;
    int qt = (u < 8) ? (15 - u) : (u - 8);  // heavy first; pairs sum constant

    int tid = threadIdx.x;
    int w = tid >> 6;
    int lane = tid & 63;
    int l31 = lane & 31;
    int hs = lane >> 5;

    size_t base = (size_t)bh * T_DIM * 64;

    // Q B-frags in registers for the whole block
    bf16x8 qBh[4], qBl[4];
    {
        size_t qoff = base + (size_t)(qt * 128 + w * 32 + l31) * 64 + hs * 8;
#pragma unroll
        for (int st = 0; st < 4; ++st) {
            qBh[st] = *reinterpret_cast<const bf16x8*>(qh_g + qoff + st * 16);
            qBl[st] = *reinterpret_cast<const bf16x8*>(ql_g + qoff + st * 16);
        }
    }

    f32x16 oacc0 = zero16(), oacc1 = zero16();   // O^T frags: col=q(lane), regs=d
    float m = -1e30f, lsum = 0.f;

    int r8 = lane >> 3, c7 = lane & 7;
    int csrcK = c7 ^ r8;                 // KH source swizzle (row&7 == r8)
    int d4 = lane >> 4, s15 = lane & 15;

    // ---- staging: swizzled content, linear dest (global_load_lds) ----
    auto stage = [&](int bs, int rt) {
        unsigned char* KH = smem + bs * 32768;
        unsigned char* VT = smem + bs * 32768 + 16384;
#pragma unroll
        for (int ci = 0; ci < 4; ++ci) {
            int chunk = w * 4 + ci;
            int row = chunk * 8 + r8;
            gload16(kh_g + base + (size_t)(rt * 128 + row) * 64 + csrcK * 8,
                    KH + chunk * 1024 + lane * 16);
        }
#pragma unroll
        for (int ci = 0; ci < 4; ++ci) {
            int chunk = w * 4 + ci;
            int d = chunk * 4 + d4;
            int cdat = (s15 & 8) | ((s15 ^ d) & 7);
            gload16(vT_g + base + (size_t)d * T_DIM + rt * 128 + cdat * 8,
                    VT + chunk * 1024 + lane * 16);
        }
    };

    stage(0, 0);
    __syncthreads();   // drain prologue stage

    for (int rt = 0; rt <= qt; ++rt) {
        if (rt < qt) stage((rt + 1) & 1, rt + 1);   // prefetch next (not waited)
        const unsigned char* KH = smem + (rt & 1) * 32768;
        const unsigned char* VT = smem + (rt & 1) * 32768 + 16384;

        int kmax = (rt == qt) ? w : 3;
        for (int kt = 0; kt <= kmax; ++kt) {
            // ---- S^T = K' x Q (hi + lo): D[krow][q], col=q=l31 ----
            int krow = kt * 32 + l31;
            f32x16 s = zero16();
#pragma unroll
            for (int st = 0; st < 4; ++st) {
                int slot = (st * 2 + hs) ^ (krow & 7);
                bf16x8 kf = *reinterpret_cast<const bf16x8*>(KH + krow * 128 + slot * 16);
                s = MFMA32(kf, qBh[st], s);
                s = MFMA32(kf, qBl[st], s);
            }
            if (rt == qt && kt == w) {
#pragma unroll
                for (int r = 0; r < 16; ++r) {
                    int rowp = (r & 3) + 8 * (r >> 2) + 4 * hs;
                    if (rowp > l31) s[r] = -1e30f;   // mask krow > q
                }
            }
            // ---- online softmax (lane-local q-row; cross only lane^32) ----
            float pmax = s[0];
#pragma unroll
            for (int r = 1; r < 16; ++r) pmax = fmaxf(pmax, s[r]);
            pmax = fmaxf(pmax, __shfl_xor(pmax, 32));
            if (__ballot(pmax > m)) {
                float mn = fmaxf(m, pmax);
                float sc = __builtin_amdgcn_exp2f(m - mn);
                m = mn; lsum *= sc;
#pragma unroll
                for (int r = 0; r < 16; ++r) { oacc0[r] *= sc; oacc1[r] *= sc; }
            }
            float p[16], psum = 0.f;
#pragma unroll
            for (int r = 0; r < 16; ++r) {
                p[r] = __builtin_amdgcn_exp2f(s[r] - m);
                psum += p[r];
            }
            lsum += psum + __shfl_xor(psum, 32);

            // ---- P -> bf16 PV frags in-register (cvt_pk + permlane32_swap) ----
            unsigned int wp[8];
#pragma unroll
            for (int q2 = 0; q2 < 2; ++q2) {
                int o = q2 * 8, d2 = q2 * 4;
                asm("v_cvt_pk_bf16_f32 %0, %1, %2" : "=v"(wp[d2+0]) : "v"(p[o+0]), "v"(p[o+1]));
                asm("v_cvt_pk_bf16_f32 %0, %1, %2" : "=v"(wp[d2+1]) : "v"(p[o+2]), "v"(p[o+3]));
                asm("v_cvt_pk_bf16_f32 %0, %1, %2" : "=v"(wp[d2+2]) : "v"(p[o+4]), "v"(p[o+5]));
                asm("v_cvt_pk_bf16_f32 %0, %1, %2" : "=v"(wp[d2+3]) : "v"(p[o+6]), "v"(p[o+7]));
                asm("v_permlane32_swap_b32 %0, %1" : "+v"(wp[d2+0]), "+v"(wp[d2+2]));
                asm("v_permlane32_swap_b32 %0, %1" : "+v"(wp[d2+1]), "+v"(wp[d2+3]));
            }
            // ---- PV: O^T += V^T x P^T ----
#pragma unroll
            for (int half = 0; half < 2; ++half) {
                union { unsigned int u[4]; bf16x8 v; } pa;
                pa.u[0] = wp[half*4+0]; pa.u[1] = wp[half*4+1];
                pa.u[2] = wp[half*4+2]; pa.u[3] = wp[half*4+3];
#pragma unroll
                for (int dt = 0; dt < 2; ++dt) {
                    int d = dt * 32 + l31;
                    int c = kt * 4 + half * 2 + hs;
                    int slot = (c & 8) | ((c ^ d) & 7);
                    bf16x8 vb = *reinterpret_cast<const bf16x8*>(VT + d * 256 + slot * 16);
                    if (dt == 0) oacc0 = MFMA32(vb, pa.v, oacc0);
                    else         oacc1 = MFMA32(vb, pa.v, oacc1);
                }
            }
        }
        __syncthreads();   // drains prefetch + all LDS reads of this buffer done
    }

    // ---- epilogue: normalize (lane-local), stage OT[d][q], store attT bf16 ----
    float inv = 1.f / lsum;
#pragma unroll
    for (int r = 0; r < 16; ++r) {
        int rowp = (r & 3) + 8 * (r >> 2) + 4 * hs;   // d-row within 32
        OT[(rowp)      * 132 + w * 32 + l31] = oacc0[r] * inv;
        OT[(32 + rowp) * 132 + w * 32 + l31] = oacc1[r] * inv;
    }
    __syncthreads();
    {
        int d = tid >> 2, qb = tid & 3;
        unsigned short tmp[32];
#pragma unroll
        for (int i = 0; i < 8; ++i) {
            f32x4 v = *reinterpret_cast<const f32x4*>(&OT[d * 132 + qb * 32 + i * 4]);
            tmp[i*4+0] = f2bf(v[0]); tmp[i*4+1] = f2bf(v[1]);
            tmp[i*4+2] = f2bf(v[2]); tmp[i*4+3] = f2bf(v[3]);
        }
        unsigned short* dst = attT + ((size_t)bh * 64 + d) * T_DIM + qt * 128 + qb * 32;
        *reinterpret_cast<u16x8*>(dst)      = *reinterpret_cast<u16x8*>(&tmp[0]);
        *reinterpret_cast<u16x8*>(dst + 8)  = *reinterpret_cast<u16x8*>(&tmp[8]);
        *reinterpret_cast<u16x8*>(dst + 16) = *reinterpret_cast<u16x8*>(&tmp[16]);
        *reinterpret_cast<u16x8*>(dst + 24) = *reinterpret_cast<u16x8*>(&tmp[24]);
    }
}

// ---------------- Kernel 3: out = attT(as [4096][1024]) @ Wr^T + br ----------
// Register-staged async prefetch: issue loads(kt+1) before compute(kt).
__global__ __launch_bounds__(256) void final_gemm_mfma(
    const unsigned short* __restrict__ A, const unsigned short* __restrict__ Bw,
    const float* __restrict__ br, float* __restrict__ out)
{
    __shared__ __align__(16) unsigned short gsm[9216];
    int nt = blockIdx.x;
    int mt = blockIdx.y;
    int tid = threadIdx.x;
    int w = tid >> 6;
    int lane = tid & 63;
    int l15 = lane & 15;
    int l4 = lane >> 4;
    int ch = tid & 7;

    f32x4 acc[4];
#pragma unroll
    for (int n = 0; n < 4; ++n) acc[n] = (f32x4){0.f, 0.f, 0.f, 0.f};

    u16x8 rr[4];
#pragma unroll
    for (int k2 = 0; k2 < 4; ++k2) {
        int row = ((tid >> 3) + 32 * k2) & 63;
        const unsigned short* src = (k2 >= 2)
            ? Bw + (size_t)(nt * 64 + row) * 1024 + ch * 8
            : A  + (size_t)(mt * 64 + row) * 1024 + ch * 8;
        rr[k2] = *reinterpret_cast<const u16x8*>(src);
    }

#pragma unroll
    for (int kt = 0; kt < 16; ++kt) {
        // commit staged registers to LDS
#pragma unroll
        for (int k2 = 0; k2 < 4; ++k2) {
            int row = ((tid >> 3) + 32 * k2) & 63;
            *reinterpret_cast<u16x8*>(&gsm[(k2 >> 1) * 4608 + row * 72 + ch * 8]) = rr[k2];
        }
        __syncthreads();
        // issue next tile's loads (latency hidden under compute)
        u16x8 rnext[4];
        if (kt < 15) {
#pragma unroll
            for (int k2 = 0; k2 < 4; ++k2) {
                int row = ((tid >> 3) + 32 * k2) & 63;
                const unsigned short* src = (k2 >= 2)
                    ? Bw + (size_t)(nt * 64 + row) * 1024 + (kt + 1) * 64 + ch * 8
                    : A  + (size_t)(mt * 64 + row) * 1024 + (kt + 1) * 64 + ch * 8;
                rnext[k2] = *reinterpret_cast<const u16x8*>(src);
            }
        }
        bf16x8 a0 = *reinterpret_cast<const bf16x8*>(&gsm[(w * 16 + l15) * 72 + l4 * 8]);
        bf16x8 a1 = *reinterpret_cast<const bf16x8*>(&gsm[(w * 16 + l15) * 72 + 32 + l4 * 8]);
#pragma unroll
        for (int n = 0; n < 4; ++n) {
            bf16x8 b0 = *reinterpret_cast<const bf16x8*>(&gsm[4608 + (n * 16 + l15) * 72 + l4 * 8]);
            bf16x8 b1 = *reinterpret_cast<const bf16x8*>(&gsm[4608 + (n * 16 + l15) * 72 + 32 + l4 * 8]);
            acc[n] = MFMA16(a0, b0, acc[n]);
            acc[n] = MFMA16(a1, b1, acc[n]);
        }
        __syncthreads();   // LDS reads done before next commit
#pragma unroll
        for (int k2 = 0; k2 < 4; ++k2) rr[k2] = rnext[k2];
    }

#pragma unroll
    for (int n = 0; n < 4; ++n) {
        int col = nt * 64 + n * 16 + l15;
        float bias = br[col];
#pragma unroll
        for (int r = 0; r < 4; ++r) {
            int row = mt * 64 + w * 16 + l4 * 4 + r;
            out[(size_t)row * 1024 + col] = acc[n][r] + bias;
        }
    }
}

extern "C" void kernel_launch(void* const* d_in, const int* in_sizes, int n_in,
                              void* d_out, int out_size, void* d_ws, size_t ws_size,
                              hipStream_t stream) {
    const float* x  = (const float*)d_in[0];
    const float* Wq = (const float*)d_in[1];
    const float* Wk = (const float*)d_in[2];
    const float* Wv = (const float*)d_in[3];
    const float* Er = (const float*)d_in[4];
    const float* Wr = (const float*)d_in[5];
    const float* br = (const float*)d_in[6];
    float* out = (float*)d_out;

    const size_t nQ = (size_t)B_DIM * H_DIM * T_DIM * S_DIM;   // 4,194,304
    char* p = (char*)d_ws;
    float* ErT = (float*)p;                   p += (size_t)T_DIM * S_DIM * 4;
    unsigned short* qh = (unsigned short*)p;  p += nQ * 2;
    unsigned short* ql = (unsigned short*)p;  p += nQ * 2;
    unsigned short* kh = (unsigned short*)p;  p += nQ * 2;
    unsigned short* vT = (unsigned short*)p;  p += nQ * 2;
    unsigned short* attT = (unsigned short*)p; p += nQ * 2;
    unsigned short* wrb = (unsigned short*)p;  p += (size_t)E_DIM * E_DIM * 2;
    unsigned short* whi = (unsigned short*)p;  p += (size_t)3 * 65536 * 2;
    unsigned short* wlo = (unsigned short*)p;  p += (size_t)3 * 65536 * 2;
    size_t need = (size_t)(p - (char*)d_ws);
    if (ws_size < need) {
        fprintf(stderr, "WS TOO SMALL: have %zu need %zu\n", ws_size, need);
        return;
    }

    er_transpose<<<512, 256, 0, stream>>>(Er, ErT);
    split_w<<<768, 256, 0, stream>>>(Wq, Wk, Wv, whi, wlo);
    convert_bf16_4<<<1024, 256, 0, stream>>>(Wr, wrb);
    qkv_mfma<<<4096, 64, 0, stream>>>(x, whi, wlo, ErT, qh, ql, kh, vT);
    attn_mfma32<<<512, 256, 0, stream>>>(qh, ql, kh, vT, attT);
    final_gemm_mfma<<<dim3(16, 64), 256, 0, stream>>>(attT, wrb, br, out);
}